// Round 1
// baseline (60.957 us; speedup 1.0000x reference)
//
#include <hip/hip_runtime.h>
#include <hip/hip_bf16.h>

// RoPE: out[b,s,2j]   = cos[pos,j]*x[b,s,2j] - sin[pos,j]*x[b,s,2j+1]
//       out[b,s,2j+1] = sin[pos,j]*x[b,s,2j] + cos[pos,j]*x[b,s,2j+1]
// D_K = 128 -> 64 pairs -> 32 float4 per row.

#define DK 128
#define F4_PER_ROW (DK / 4)   // 32

__global__ void rope_f32_kernel(const float* __restrict__ x,
                                const int* __restrict__ pos,
                                const float* __restrict__ sin_tab,
                                const float* __restrict__ cos_tab,
                                float* __restrict__ out,
                                long n4) {
    long idx = (long)blockIdx.x * blockDim.x + threadIdx.x;
    const long stride = (long)gridDim.x * blockDim.x;
    for (; idx < n4; idx += stride) {
        const long row = idx >> 5;          // idx / F4_PER_ROW
        const int  f4  = (int)(idx & 31);   // which float4 within the row
        const int  p   = pos[row];

        const float4 xv = reinterpret_cast<const float4*>(x)[idx];

        const long tbase = (long)p * (DK / 2) + f4 * 2;   // pair index j0
        const float2 s = *reinterpret_cast<const float2*>(&sin_tab[tbase]);
        const float2 c = *reinterpret_cast<const float2*>(&cos_tab[tbase]);

        float4 o;
        o.x = c.x * xv.x - s.x * xv.y;
        o.y = s.x * xv.x + c.x * xv.y;
        o.z = c.y * xv.z - s.y * xv.w;
        o.w = s.y * xv.z + c.y * xv.w;

        reinterpret_cast<float4*>(out)[idx] = o;
    }
}

extern "C" void kernel_launch(void* const* d_in, const int* in_sizes, int n_in,
                              void* d_out, int out_size, void* d_ws, size_t ws_size,
                              hipStream_t stream) {
    const float* x       = (const float*)d_in[0];
    const int*   posp    = (const int*)d_in[1];
    const float* sin_tab = (const float*)d_in[2];
    const float* cos_tab = (const float*)d_in[3];
    float*       out     = (float*)d_out;

    const long n4 = (long)out_size / 4;     // total float4 count

    const int block = 256;
    long blocks_needed = (n4 + block - 1) / block;
    int grid = (int)(blocks_needed < 2048 ? blocks_needed : 2048);

    rope_f32_kernel<<<grid, block, 0, stream>>>(x, posp, sin_tab, cos_tab, out, n4);
}

// Round 3
// 51.472 us; speedup vs baseline: 1.1843x; 1.1843x over previous
//
#include <hip/hip_runtime.h>
#include <hip/hip_bf16.h>

// RoPE: out[b,s,2j]   = cos[pos,j]*x[b,s,2j] - sin[pos,j]*x[b,s,2j+1]
//       out[b,s,2j+1] = sin[pos,j]*x[b,s,2j] + cos[pos,j]*x[b,s,2j+1]
// D_K = 128 -> 64 pairs -> 32 float4 per row.
//
// R2: same as R1 but with native clang vector types so the nontemporal
// builtins compile (HIP_vector_type float4 is rejected).

#define DK 128
#define UNROLL 4

typedef float f32x4 __attribute__((ext_vector_type(4)));
typedef float f32x2 __attribute__((ext_vector_type(2)));

__global__ __launch_bounds__(256)
void rope_f32_kernel(const float* __restrict__ x,
                     const int* __restrict__ pos,
                     const float* __restrict__ sin_tab,
                     const float* __restrict__ cos_tab,
                     float* __restrict__ out,
                     long n4) {
    const long base = (long)blockIdx.x * (256 * UNROLL) + threadIdx.x;
    const f32x4* __restrict__ xv4 = reinterpret_cast<const f32x4*>(x);
    f32x4* __restrict__ ov4 = reinterpret_cast<f32x4*>(out);

    long idx[UNROLL];
    int  p[UNROLL];
    f32x4 xv[UNROLL];
    f32x2 s[UNROLL], c[UNROLL];

    // 1) issue all pos loads (independent)
    #pragma unroll
    for (int k = 0; k < UNROLL; ++k) {
        idx[k] = base + k * 256;
        p[k] = pos[idx[k] >> 5];           // row = idx / 32
    }
    // 2) issue all x loads (independent of pos)
    #pragma unroll
    for (int k = 0; k < UNROLL; ++k) {
        xv[k] = __builtin_nontemporal_load(&xv4[idx[k]]);
    }
    // 3) table loads (dependent on pos, 4 chains in flight)
    #pragma unroll
    for (int k = 0; k < UNROLL; ++k) {
        const int  f4    = (int)(idx[k] & 31);
        const long tbase = (long)p[k] * (DK / 2) + f4 * 2;
        s[k] = *reinterpret_cast<const f32x2*>(&sin_tab[tbase]);
        c[k] = *reinterpret_cast<const f32x2*>(&cos_tab[tbase]);
    }
    // 4) compute + store
    #pragma unroll
    for (int k = 0; k < UNROLL; ++k) {
        f32x4 o;
        o.x = c[k].x * xv[k].x - s[k].x * xv[k].y;
        o.y = s[k].x * xv[k].x + c[k].x * xv[k].y;
        o.z = c[k].y * xv[k].z - s[k].y * xv[k].w;
        o.w = s[k].y * xv[k].z + c[k].y * xv[k].w;
        __builtin_nontemporal_store(o, &ov4[idx[k]]);
    }
}

extern "C" void kernel_launch(void* const* d_in, const int* in_sizes, int n_in,
                              void* d_out, int out_size, void* d_ws, size_t ws_size,
                              hipStream_t stream) {
    const float* x       = (const float*)d_in[0];
    const int*   posp    = (const int*)d_in[1];
    const float* sin_tab = (const float*)d_in[2];
    const float* cos_tab = (const float*)d_in[3];
    float*       out     = (float*)d_out;

    const long n4 = (long)out_size / 4;              // total float4 count
    const long per_block = 256 * UNROLL;
    const int grid = (int)((n4 + per_block - 1) / per_block);  // exact: 8192

    rope_f32_kernel<<<grid, 256, 0, stream>>>(x, posp, sin_tab, cos_tab, out, n4);
}